// Round 7
// baseline (224.448 us; speedup 1.0000x reference)
//
#include <hip/hip_runtime.h>
#include <hip/hip_fp16.h>
#include <math.h>

// B=65536 rows, DIM=256, OUT=10.
// z = x@w_in + b_in; 4x { z = (z + tanh(z) + b_i) @ inv(W_i) }; out = softmax(z@w_out + b_out).
// Newton on a linear system converges in one step => z = c @ W^{-1}.
// Round 21: REVERT to round-10/R0 winner (fused_k MT=4, 4 blocks/CU, 64 arch + 64
// AGPR = exactly the 128-unified/wave budget at 4 waves/SIMD) + ONE fix:
//   1-kc-lookahead wh rotation. R0's stall: per-layer barrier puts all 16 waves/CU
//   in lockstep; each kc step = 4 global wh loads -> vmcnt burst wait (~300cy) ->
//   155cy MFMA, waits synchronized across waves -> MfmaUtil 24%. Now WLOAD(k+1)
//   issues before MFMA(k) (named whA/whB, literal indices, rule #20), one
//   sched_barrier(0) per region pins live wh at 32 regs (R15 hoist guard).
//   Live arch: whA 16 + whB 16 + zf 16 + addr ~12 = ~60 <= 64 -> no spill.
//   + s_setprio(1) around MFMA clusters (4 desynced blocks/CU = T5's regime).
//   R15-R20 lesson: unified pool = 512 regs/SIMD; >128/wave needs <4 waves/SIMD ->
//   register-resident-weight designs all spill or lose occupancy. Direction closed.

typedef __attribute__((ext_vector_type(8))) short short8;
typedef __attribute__((ext_vector_type(4))) float f32x4;

// ---- helpers ----
__device__ __forceinline__ float tanh_fast(float x) {
#if __has_builtin(__builtin_amdgcn_exp2f)
  float e = __builtin_amdgcn_exp2f(x * 2.8853900817779268f);
#else
  float e = __expf(2.0f * x);
#endif
  return 1.0f - 2.0f * __builtin_amdgcn_rcpf(e + 1.0f);
}
// RNE pair pack (cold path: weights)
__device__ __forceinline__ unsigned rn_pair16(float v0, float v1) {
  __half2 h = __floats2half2_rn(v0, v1);
  return *reinterpret_cast<unsigned*>(&h);
}
// RTZ pair pack, single v_cvt_pkrtz (hot path: z)
__device__ __forceinline__ unsigned rtz_pair16(float v0, float v1) {
#if __has_builtin(__builtin_amdgcn_cvt_pkrtz)
  typedef __fp16 h2v __attribute__((ext_vector_type(2)));
  h2v h = __builtin_amdgcn_cvt_pkrtz(v0, v1);
  return *reinterpret_cast<unsigned*>(&h);
#else
  return rn_pair16(v0, v1);
#endif
}

// ---------------- Phase 1: one kernel, 384 blocks (proven) ----------------
// Blocks 0..255: matrix m = bid>>6, 4-row slab r0 = (bid&63)*4:
//   P = 6I -15W +20W^2 -15W^3 +6W^4 -W^5 via 4 Horner steps (mult by original W);
//   pack fp16-RNE into pk layer m+1.
// Blocks 256..383: pack w_in + w_out (at 5*32768, cols>=10 zero).
// pk layout (dwords): layer*32768 + kc*4096 + nt*256 + lane*4 + d;
// word d of lane(quad,n16) = M[kb][n] lo16 | M[kb+1][n] hi16, kb=kc*32+quad*8+2d, n=nt*16+n16.
__global__ __launch_bounds__(256) void ns_poly_k(
    const float* __restrict__ w1, const float* __restrict__ w2,
    const float* __restrict__ w3, const float* __restrict__ w4,
    const float* __restrict__ w_in, const float* __restrict__ w_out,
    unsigned* __restrict__ pk) {
  const int bid = blockIdx.x;
  const int t = threadIdx.x;
  if (bid >= 256) {
    int idx = (bid - 256) * 256 + t;  // 0..32767
    {
      int kc = idx >> 12;
      int nt = (idx >> 8) & 15;
      int lane = (idx >> 2) & 63;
      int d = idx & 3;
      int n = nt * 16 + (lane & 15);
      int kb = kc * 32 + (lane >> 4) * 8 + d * 2;
      pk[idx] = rn_pair16(w_in[kb * 256 + n], w_in[(kb + 1) * 256 + n]);
    }
    int idx2 = idx + 32768;
    if (idx2 < 34816) {
      int r2 = idx2 - 32768;  // 0..2047
      int kc = r2 >> 8;
      int lane = (r2 >> 2) & 63;
      int d = r2 & 3;
      int n = lane & 15;
      int kb = kc * 32 + (lane >> 4) * 8 + d * 2;
      float v0 = (n < 10) ? w_out[kb * 10 + n] : 0.0f;
      float v1 = (n < 10) ? w_out[(kb + 1) * 10 + n] : 0.0f;
      pk[5 * 32768 + r2] = rn_pair16(v0, v1);
    }
    return;
  }
  const int m = bid >> 6;           // matrix 0..3
  const int r0 = (bid & 63) * 4;    // slab start row (4 rows)
  const float* __restrict__ W = (m == 0) ? w1 : (m == 1) ? w2 : (m == 2) ? w3 : w4;
  __shared__ float S[4][256];

  // init: P = 6I - W (slab rows r0..r0+3)
#pragma unroll
  for (int i = 0; i < 4; ++i) {
    int e = i * 256 + t;
    int r = e >> 8, c = e & 255;
    S[r][c] = (((r0 + r) == c) ? 6.0f : 0.0f) - W[(r0 + r) * 256 + c];
  }
  __syncthreads();

  const float coef[4] = {-15.0f, 20.0f, -15.0f, 6.0f};
#pragma unroll
  for (int step = 0; step < 4; ++step) {
    float acc[4];
#pragma unroll
    for (int r = 0; r < 4; ++r) acc[r] = 0.0f;
    for (int k = 0; k < 256; k += 4) {
      float4 sv[4];
#pragma unroll
      for (int r = 0; r < 4; ++r) sv[r] = *(const float4*)&S[r][k];
      float wv0 = W[(k + 0) * 256 + t];
      float wv1 = W[(k + 1) * 256 + t];
      float wv2 = W[(k + 2) * 256 + t];
      float wv3 = W[(k + 3) * 256 + t];
#pragma unroll
      for (int r = 0; r < 4; ++r) {
        acc[r] = fmaf(sv[r].x, wv0, acc[r]);
        acc[r] = fmaf(sv[r].y, wv1, acc[r]);
        acc[r] = fmaf(sv[r].z, wv2, acc[r]);
        acc[r] = fmaf(sv[r].w, wv3, acc[r]);
      }
    }
    __syncthreads();
    float cdiag = coef[step];
#pragma unroll
    for (int r = 0; r < 4; ++r)
      S[r][t] = acc[r] + (((r0 + r) == t) ? cdiag : 0.0f);
    __syncthreads();
  }

  // ---- pack slab: kc = r0>>5, quad = (r0>>3)&3, d in {d0, d0+1}, d0 = (r0&7)>>1 ----
  const int kc = r0 >> 5;
  const int quad = (r0 >> 3) & 3;
  const int d0 = (r0 & 7) >> 1;
#pragma unroll
  for (int i = 0; i < 2; ++i) {
    int q = i * 256 + t;        // 0..511 = nt*32 + n16*2 + dd
    int nt = q >> 5;            // 0..15
    int n16 = (q >> 1) & 15;
    int dd = q & 1;
    int n = nt * 16 + n16;
    int lane = quad * 16 + n16;
    unsigned word = rn_pair16(S[2 * dd][n], S[2 * dd + 1][n]);
    pk[(m + 1) * 32768 + kc * 4096 + nt * 256 + lane * 4 + (d0 + dd)] = word;
  }
}

// ---------------- Phase 2: fused_k (R0 base + 1-kc-lookahead wh rotation) ----------------
// Load the 4 wh fragments for step KC of LAYER into named buffer W (16 VGPRs).
#define WLOAD(W, LAYER, KC)                                                    \
  {                                                                            \
    const unsigned* pb_ = pk + (LAYER) * 32768 + (KC) * 4096 + wv * 1024 + ln * 4; \
    W[0] = *(const short8*)(pb_);                                              \
    W[1] = *(const short8*)(pb_ + 256);                                        \
    W[2] = *(const short8*)(pb_ + 512);                                        \
    W[3] = *(const short8*)(pb_ + 768);                                        \
  }

// One kc step: read zf (LDS), 16 MFMAs from named buffer W (literal KC, rule #20).
// setprio(1) around the MFMA cluster (T5; 4 desynced blocks/CU).
#define STEP(W, KC)                                                            \
  {                                                                            \
    short8 zf[4];                                                              \
    _Pragma("unroll") for (int mt = 0; mt < 4; ++mt) {                         \
      int mm = mt * 16 + n16;                                                  \
      zf[mt] = *(const short8*)&zpl[mm * 256 + ((((KC) * 4 + quad) ^ (mm & 31)) * 8)]; \
    }                                                                          \
    __builtin_amdgcn_s_setprio(1);                                             \
    _Pragma("unroll") for (int mt = 0; mt < 4; ++mt)                           \
      _Pragma("unroll") for (int nt = 0; nt < 4; ++nt)                         \
        acc[mt][nt] = __builtin_amdgcn_mfma_f32_16x16x32_f16(                  \
            W[nt], zf[mt], acc[mt][nt], 0, 0, 0);                              \
    __builtin_amdgcn_s_setprio(0);                                             \
  }
#define SB __builtin_amdgcn_sched_barrier(0)

template <int MT>
__global__ __launch_bounds__(256, 4) void fused_k(
    const float* __restrict__ x, const unsigned* __restrict__ pk,
    const float* __restrict__ b_in,
    const float* __restrict__ b1, const float* __restrict__ b2,
    const float* __restrict__ b3, const float* __restrict__ b4,
    const float* __restrict__ b_out, float* __restrict__ out) {
  constexpr int NR = MT * 16;
  __shared__ unsigned short zpl[NR * 256];  // 32 KB for MT=4
  const int t = threadIdx.x;
  const int ln = t & 63;
  const int wv = t >> 6;
  const int quad = ln >> 4;
  const int n16 = ln & 15;
  const int grow0 = blockIdx.x * NR;

  short8 whA[4], whB[4];
  // prologue: layer-0 kc0 wh loads in flight during x staging
  WLOAD(whA, 0, 0);

  // ---- stage x as fp16 plane ----
#pragma unroll
  for (int i = 0; i < MT * 4; ++i) {
    int e = i * 1024 + t * 4;
    int r = e >> 8, c = e & 255;
    float4 v = *(const float4*)(x + (grow0 + r) * 256 + c);
    int idx = r * 256 + (((c >> 3) ^ (r & 31)) * 8) + (c & 7);
    uint2 zp;
    zp.x = rtz_pair16(v.x, v.y);
    zp.y = rtz_pair16(v.z, v.w);
    *(uint2*)&zpl[idx] = zp;
  }
  __syncthreads();

  const float* bnv[4] = {b1, b2, b3, b4};
  f32x4 acc[MT][4];

  for (int layer = 0; layer < 5; ++layer) {
#pragma unroll
    for (int mt = 0; mt < MT; ++mt)
#pragma unroll
      for (int nt = 0; nt < 4; ++nt) acc[mt][nt] = (f32x4){0.f, 0.f, 0.f, 0.f};

    // 1-kc lookahead: WLOAD(k+1) issues before MFMA(k); SB pins live wh at 32 regs.
    WLOAD(whB, layer, 1); STEP(whA, 0); SB;
    WLOAD(whA, layer, 2); STEP(whB, 1); SB;
    WLOAD(whB, layer, 3); STEP(whA, 2); SB;
    WLOAD(whA, layer, 4); STEP(whB, 3); SB;
    WLOAD(whB, layer, 5); STEP(whA, 4); SB;
    WLOAD(whA, layer, 6); STEP(whB, 5); SB;
    WLOAD(whB, layer, 7); STEP(whA, 6); SB;
    STEP(whB, 7);
    __syncthreads();  // all z reads of this layer done

    // prefetch next layer's kc0 (lands during epilogue; barrier drain ~free)
    if (layer < 4) WLOAD(whA, layer + 1, 0);

    // epilogue: lane owns rows mt*16+n16, cols colb..colb+3 (one b64 write each)
#pragma unroll
    for (int nt = 0; nt < 4; ++nt) {
      int colb = wv * 64 + nt * 16 + quad * 4;
      float4 bi = make_float4(0.f, 0.f, 0.f, 0.f);
      float4 bn4 = bi;
      if (layer == 0) bi = *(const float4*)(b_in + colb);
      if (layer < 4) bn4 = *(const float4*)(bnv[layer] + colb);
#pragma unroll
      for (int mt = 0; mt < MT; ++mt) {
        int row = mt * 16 + n16;
        float v0 = acc[mt][nt][0] + bi.x;
        float v1 = acc[mt][nt][1] + bi.y;
        float v2 = acc[mt][nt][2] + bi.z;
        float v3 = acc[mt][nt][3] + bi.w;
        if (layer < 4) {
          v0 = v0 + tanh_fast(v0) + bn4.x;
          v1 = v1 + tanh_fast(v1) + bn4.y;
          v2 = v2 + tanh_fast(v2) + bn4.z;
          v3 = v3 + tanh_fast(v3) + bn4.w;
        }
        int idx = row * 256 + (((colb >> 3) ^ (row & 31)) * 8) + (colb & 7);
        uint2 zp;
        zp.x = rtz_pair16(v0, v1);
        zp.y = rtz_pair16(v2, v3);
        *(uint2*)&zpl[idx] = zp;
      }
    }
    __syncthreads();
  }

  // ---- logits: wave w reduces k-slice [w*64, w*64+64) ----
  f32x4 lacc[MT];
#pragma unroll
  for (int mt = 0; mt < MT; ++mt) lacc[mt] = (f32x4){0.f, 0.f, 0.f, 0.f};
  const unsigned* pw = pk + 5 * 32768 + ln * 4;
#pragma unroll
  for (int kk = 0; kk < 2; ++kk) {
    int kc = wv * 2 + kk;
    short8 wh = *(const short8*)(pw + kc * 256);
#pragma unroll
    for (int mt = 0; mt < MT; ++mt) {
      int mm = mt * 16 + n16;
      int idx = mm * 256 + (((kc * 4 + quad) ^ (mm & 31)) * 8);
      short8 zf = *(const short8*)&zpl[idx];
      lacc[mt] = __builtin_amdgcn_mfma_f32_16x16x32_f16(wh, zf, lacc[mt], 0, 0, 0);
    }
  }
  __syncthreads();  // done reading z plane
  float* pbuf = (float*)zpl;  // [wave][NR][16] floats = 16 KB for MT=4
#pragma unroll
  for (int mt = 0; mt < MT; ++mt) {
    int addr = wv * (NR * 16) + (mt * 16 + n16) * 16 + quad * 4;
    *(f32x4*)&pbuf[addr] = lacc[mt];
  }
  __syncthreads();
  if (t < NR) {
    int r = t;
    float lg[10];
    float mx = -1e30f;
#pragma unroll
    for (int j = 0; j < 10; ++j) {
      float s = b_out[j];
#pragma unroll
      for (int w2 = 0; w2 < 4; ++w2) s += pbuf[w2 * (NR * 16) + r * 16 + j];
      lg[j] = s;
      mx = fmaxf(mx, s);
    }
    float sum = 0.f;
#pragma unroll
    for (int j = 0; j < 10; ++j) {
      lg[j] = __expf(lg[j] - mx);
      sum += lg[j];
    }
    float inv = 1.0f / sum;
    float* op = out + (grow0 + r) * 10;
#pragma unroll
    for (int j = 0; j < 10; ++j) op[j] = lg[j] * inv;
  }
}

extern "C" void kernel_launch(void* const* d_in, const int* in_sizes, int n_in,
                              void* d_out, int out_size, void* d_ws, size_t ws_size,
                              hipStream_t stream) {
  const float* x     = (const float*)d_in[0];
  const float* w_in  = (const float*)d_in[1];
  const float* b_in  = (const float*)d_in[2];
  const float* w_out = (const float*)d_in[3];
  const float* b_out = (const float*)d_in[4];
  const float* w1 = (const float*)d_in[5];
  const float* b1 = (const float*)d_in[6];
  const float* w2 = (const float*)d_in[7];
  const float* b2 = (const float*)d_in[8];
  const float* w3 = (const float*)d_in[9];
  const float* b3 = (const float*)d_in[10];
  const float* w4 = (const float*)d_in[11];
  const float* b4 = (const float*)d_in[12];
  float* out = (float*)d_out;

  unsigned* pk = (unsigned*)d_ws;  // 165888 dwords

  ns_poly_k<<<384, 256, 0, stream>>>(w1, w2, w3, w4, w_in, w_out, pk);
  fused_k<4><<<1024, 256, 0, stream>>>(x, pk, b_in, b1, b2, b3, b4, b_out, out);
}

// Round 8
// 181.264 us; speedup vs baseline: 1.2382x; 1.2382x over previous
//
#include <hip/hip_runtime.h>
#include <hip/hip_fp16.h>
#include <math.h>

// B=65536 rows, DIM=256, OUT=10.
// z = x@w_in + b_in; 4x { z = (z + tanh(z) + b_i) @ inv(W_i) }; out = softmax(z@w_out + b_out).
// Newton on a linear system converges in one step => z = c @ W^{-1}.
// Round 22: fused_k = EXACT round-10/R0 winner (73us, 64 arch + 64 AGPR = the full
// 128-unified budget at 4 waves/SIMD; R15-R21 proved ANY register growth spills).
// ns_poly_k: the other ~40-110us. Was 1 wave/SIMD + non-unrolled k-loop ->
// ~230cyc/iter latency-naked. Now: 512-thr blocks, k-split x2 (each half does 128
// k-iters into partials, LDS-reduced per step) + unroll-4 (16 loads in flight).
// fp32 math unchanged (only summation order differs).

typedef __attribute__((ext_vector_type(8))) short short8;
typedef __attribute__((ext_vector_type(4))) float f32x4;

// ---- helpers ----
__device__ __forceinline__ float tanh_fast(float x) {
#if __has_builtin(__builtin_amdgcn_exp2f)
  float e = __builtin_amdgcn_exp2f(x * 2.8853900817779268f);
#else
  float e = __expf(2.0f * x);
#endif
  return 1.0f - 2.0f * __builtin_amdgcn_rcpf(e + 1.0f);
}
// RNE pair pack (cold path: weights)
__device__ __forceinline__ unsigned rn_pair16(float v0, float v1) {
  __half2 h = __floats2half2_rn(v0, v1);
  return *reinterpret_cast<unsigned*>(&h);
}
// RTZ pair pack, single v_cvt_pkrtz (hot path: z)
__device__ __forceinline__ unsigned rtz_pair16(float v0, float v1) {
#if __has_builtin(__builtin_amdgcn_cvt_pkrtz)
  typedef __fp16 h2v __attribute__((ext_vector_type(2)));
  h2v h = __builtin_amdgcn_cvt_pkrtz(v0, v1);
  return *reinterpret_cast<unsigned*>(&h);
#else
  return rn_pair16(v0, v1);
#endif
}

// ---------------- Phase 1: ns_poly_k, 320 blocks x 512 threads ----------------
// Blocks 0..255: matrix m = bid>>6, 4-row slab r0 = (bid&63)*4:
//   P = 6I -15W +20W^2 -15W^3 +6W^4 -W^5 via 4 Horner steps (mult by original W);
//   k-dimension split across tk=t>>8 (two halves of 128), partials LDS-reduced;
//   inner loop unroll-4 (16 W loads in flight). Pack fp16-RNE into pk layer m+1.
// Blocks 256..319 (512 thr): pack w_in + w_out (at 5*32768, cols>=10 zero).
// pk layout (dwords): layer*32768 + kc*4096 + nt*256 + lane*4 + d;
// word d of lane(quad,n16) = M[kb][n] lo16 | M[kb+1][n] hi16, kb=kc*32+quad*8+2d, n=nt*16+n16.
__global__ __launch_bounds__(512) void ns_poly_k(
    const float* __restrict__ w1, const float* __restrict__ w2,
    const float* __restrict__ w3, const float* __restrict__ w4,
    const float* __restrict__ w_in, const float* __restrict__ w_out,
    unsigned* __restrict__ pk) {
  const int bid = blockIdx.x;
  const int t = threadIdx.x;
  if (bid >= 256) {
    int idx = (bid - 256) * 512 + t;  // 0..32767
    {
      int kc = idx >> 12;
      int nt = (idx >> 8) & 15;
      int lane = (idx >> 2) & 63;
      int d = idx & 3;
      int n = nt * 16 + (lane & 15);
      int kb = kc * 32 + (lane >> 4) * 8 + d * 2;
      pk[idx] = rn_pair16(w_in[kb * 256 + n], w_in[(kb + 1) * 256 + n]);
    }
    int idx2 = idx + 32768;
    if (idx2 < 34816) {
      int r2 = idx2 - 32768;  // 0..2047
      int kc = r2 >> 8;
      int lane = (r2 >> 2) & 63;
      int d = r2 & 3;
      int n = lane & 15;
      int kb = kc * 32 + (lane >> 4) * 8 + d * 2;
      float v0 = (n < 10) ? w_out[kb * 10 + n] : 0.0f;
      float v1 = (n < 10) ? w_out[(kb + 1) * 10 + n] : 0.0f;
      pk[5 * 32768 + r2] = rn_pair16(v0, v1);
    }
    return;
  }
  const int m = bid >> 6;           // matrix 0..3
  const int r0 = (bid & 63) * 4;    // slab start row (4 rows)
  const float* __restrict__ W = (m == 0) ? w1 : (m == 1) ? w2 : (m == 2) ? w3 : w4;
  const int tk = t >> 8;            // k-half 0/1
  const int tt = t & 255;           // column
  __shared__ float S[4][256];
  __shared__ float P2[2][4][256];   // per-half partials, 8 KB

  // init: P = 6I - W (slab rows r0..r0+3); 512 threads, 2 elems each
#pragma unroll
  for (int i = 0; i < 2; ++i) {
    int e = i * 512 + t;
    int r = e >> 8, c = e & 255;
    S[r][c] = (((r0 + r) == c) ? 6.0f : 0.0f) - W[(r0 + r) * 256 + c];
  }
  __syncthreads();

  const float coef[4] = {-15.0f, 20.0f, -15.0f, 6.0f};
#pragma unroll
  for (int step = 0; step < 4; ++step) {
    float acc[4];
#pragma unroll
    for (int r = 0; r < 4; ++r) acc[r] = 0.0f;
    const float* __restrict__ Wk = W + tk * 128 * 256;
    const int kbase = tk * 128;
#pragma unroll 4
    for (int k = 0; k < 128; k += 4) {
      float4 sv[4];
#pragma unroll
      for (int r = 0; r < 4; ++r) sv[r] = *(const float4*)&S[r][kbase + k];
      float wv0 = Wk[(k + 0) * 256 + tt];
      float wv1 = Wk[(k + 1) * 256 + tt];
      float wv2 = Wk[(k + 2) * 256 + tt];
      float wv3 = Wk[(k + 3) * 256 + tt];
#pragma unroll
      for (int r = 0; r < 4; ++r) {
        acc[r] = fmaf(sv[r].x, wv0, acc[r]);
        acc[r] = fmaf(sv[r].y, wv1, acc[r]);
        acc[r] = fmaf(sv[r].z, wv2, acc[r]);
        acc[r] = fmaf(sv[r].w, wv3, acc[r]);
      }
    }
#pragma unroll
    for (int r = 0; r < 4; ++r) P2[tk][r][tt] = acc[r];
    __syncthreads();
    float cdiag = coef[step];
#pragma unroll
    for (int i = 0; i < 2; ++i) {
      int e = i * 512 + t;
      int r = e >> 8, c = e & 255;
      S[r][c] = P2[0][r][c] + P2[1][r][c] + (((r0 + r) == c) ? cdiag : 0.0f);
    }
    __syncthreads();
  }

  // ---- pack slab: kc = r0>>5, quad = (r0>>3)&3, d in {d0, d0+1}, d0 = (r0&7)>>1 ----
  const int kc = r0 >> 5;
  const int quad = (r0 >> 3) & 3;
  const int d0 = (r0 & 7) >> 1;
  {
    int q = t;                  // 0..511 = nt*32 + n16*2 + dd
    int nt = q >> 5;            // 0..15
    int n16 = (q >> 1) & 15;
    int dd = q & 1;
    int n = nt * 16 + n16;
    int lane = quad * 16 + n16;
    unsigned word = rn_pair16(S[2 * dd][n], S[2 * dd + 1][n]);
    pk[(m + 1) * 32768 + kc * 4096 + nt * 256 + lane * 4 + (d0 + dd)] = word;
  }
}

// ---------------- Phase 2: fused pipeline (round-10 winner, EXACT) ----------------
// MT*16 rows/block (MT=4 -> 64 rows, 32 KB LDS, grid 1024, 4 blocks/CU); 4 waves,
// wave w owns cols [w*64, w*64+64). z single fp16 plane, XOR swizzle:
//   idx16(r,k) = r*256 + ((k>>3) ^ (r&31))*8 + (k&7)
template <int MT>
__global__ __launch_bounds__(256, 4) void fused_k(
    const float* __restrict__ x, const unsigned* __restrict__ pk,
    const float* __restrict__ b_in,
    const float* __restrict__ b1, const float* __restrict__ b2,
    const float* __restrict__ b3, const float* __restrict__ b4,
    const float* __restrict__ b_out, float* __restrict__ out) {
  constexpr int NR = MT * 16;
  __shared__ unsigned short zpl[NR * 256];  // 32 KB for MT=4
  const int t = threadIdx.x;
  const int ln = t & 63;
  const int wv = t >> 6;
  const int quad = ln >> 4;
  const int n16 = ln & 15;
  const int grow0 = blockIdx.x * NR;

  // ---- stage x as fp16 plane ----
#pragma unroll
  for (int i = 0; i < MT * 4; ++i) {
    int e = i * 1024 + t * 4;
    int r = e >> 8, c = e & 255;
    float4 v = *(const float4*)(x + (grow0 + r) * 256 + c);
    int idx = r * 256 + (((c >> 3) ^ (r & 31)) * 8) + (c & 7);
    uint2 zp;
    zp.x = rtz_pair16(v.x, v.y);
    zp.y = rtz_pair16(v.z, v.w);
    *(uint2*)&zpl[idx] = zp;
  }
  __syncthreads();

  const float* bnv[4] = {b1, b2, b3, b4};
  f32x4 acc[MT][4];

  for (int layer = 0; layer < 5; ++layer) {
    const unsigned* pkl = pk + layer * 32768 + wv * 1024 + ln * 4;
#pragma unroll
    for (int mt = 0; mt < MT; ++mt)
#pragma unroll
      for (int nt = 0; nt < 4; ++nt) acc[mt][nt] = (f32x4){0.f, 0.f, 0.f, 0.f};

#pragma unroll 2
    for (int kc = 0; kc < 8; ++kc) {
      short8 wh[4], zf[MT];
      const unsigned* pb = pkl + kc * 4096;
#pragma unroll
      for (int nt = 0; nt < 4; ++nt) wh[nt] = *(const short8*)(pb + nt * 256);
#pragma unroll
      for (int mt = 0; mt < MT; ++mt) {
        int mm = mt * 16 + n16;
        int idx = mm * 256 + (((kc * 4 + quad) ^ (mm & 31)) * 8);
        zf[mt] = *(const short8*)&zpl[idx];
      }
#pragma unroll
      for (int mt = 0; mt < MT; ++mt)
#pragma unroll
        for (int nt = 0; nt < 4; ++nt)
          acc[mt][nt] = __builtin_amdgcn_mfma_f32_16x16x32_f16(wh[nt], zf[mt], acc[mt][nt], 0, 0, 0);
    }
    __syncthreads();  // all z reads of this layer done

    // epilogue: lane owns rows mt*16+n16, cols colb..colb+3 (one b64 write each)
#pragma unroll
    for (int nt = 0; nt < 4; ++nt) {
      int colb = wv * 64 + nt * 16 + quad * 4;
      float4 bi = make_float4(0.f, 0.f, 0.f, 0.f);
      float4 bn4 = bi;
      if (layer == 0) bi = *(const float4*)(b_in + colb);
      if (layer < 4) bn4 = *(const float4*)(bnv[layer] + colb);
#pragma unroll
      for (int mt = 0; mt < MT; ++mt) {
        int row = mt * 16 + n16;
        float v0 = acc[mt][nt][0] + bi.x;
        float v1 = acc[mt][nt][1] + bi.y;
        float v2 = acc[mt][nt][2] + bi.z;
        float v3 = acc[mt][nt][3] + bi.w;
        if (layer < 4) {
          v0 = v0 + tanh_fast(v0) + bn4.x;
          v1 = v1 + tanh_fast(v1) + bn4.y;
          v2 = v2 + tanh_fast(v2) + bn4.z;
          v3 = v3 + tanh_fast(v3) + bn4.w;
        }
        int idx = row * 256 + (((colb >> 3) ^ (row & 31)) * 8) + (colb & 7);
        uint2 zp;
        zp.x = rtz_pair16(v0, v1);
        zp.y = rtz_pair16(v2, v3);
        *(uint2*)&zpl[idx] = zp;
      }
    }
    __syncthreads();
  }

  // ---- logits: wave w reduces k-slice [w*64, w*64+64) ----
  f32x4 lacc[MT];
#pragma unroll
  for (int mt = 0; mt < MT; ++mt) lacc[mt] = (f32x4){0.f, 0.f, 0.f, 0.f};
  const unsigned* pw = pk + 5 * 32768 + ln * 4;
#pragma unroll
  for (int kk = 0; kk < 2; ++kk) {
    int kc = wv * 2 + kk;
    short8 wh = *(const short8*)(pw + kc * 256);
#pragma unroll
    for (int mt = 0; mt < MT; ++mt) {
      int mm = mt * 16 + n16;
      int idx = mm * 256 + (((kc * 4 + quad) ^ (mm & 31)) * 8);
      short8 zf = *(const short8*)&zpl[idx];
      lacc[mt] = __builtin_amdgcn_mfma_f32_16x16x32_f16(wh, zf, lacc[mt], 0, 0, 0);
    }
  }
  __syncthreads();  // done reading z plane
  float* pbuf = (float*)zpl;  // [wave][NR][16] floats = 16 KB for MT=4
#pragma unroll
  for (int mt = 0; mt < MT; ++mt) {
    int addr = wv * (NR * 16) + (mt * 16 + n16) * 16 + quad * 4;
    *(f32x4*)&pbuf[addr] = lacc[mt];
  }
  __syncthreads();
  if (t < NR) {
    int r = t;
    float lg[10];
    float mx = -1e30f;
#pragma unroll
    for (int j = 0; j < 10; ++j) {
      float s = b_out[j];
#pragma unroll
      for (int w2 = 0; w2 < 4; ++w2) s += pbuf[w2 * (NR * 16) + r * 16 + j];
      lg[j] = s;
      mx = fmaxf(mx, s);
    }
    float sum = 0.f;
#pragma unroll
    for (int j = 0; j < 10; ++j) {
      lg[j] = __expf(lg[j] - mx);
      sum += lg[j];
    }
    float inv = 1.0f / sum;
    float* op = out + (grow0 + r) * 10;
#pragma unroll
    for (int j = 0; j < 10; ++j) op[j] = lg[j] * inv;
  }
}

extern "C" void kernel_launch(void* const* d_in, const int* in_sizes, int n_in,
                              void* d_out, int out_size, void* d_ws, size_t ws_size,
                              hipStream_t stream) {
  const float* x     = (const float*)d_in[0];
  const float* w_in  = (const float*)d_in[1];
  const float* b_in  = (const float*)d_in[2];
  const float* w_out = (const float*)d_in[3];
  const float* b_out = (const float*)d_in[4];
  const float* w1 = (const float*)d_in[5];
  const float* b1 = (const float*)d_in[6];
  const float* w2 = (const float*)d_in[7];
  const float* b2 = (const float*)d_in[8];
  const float* w3 = (const float*)d_in[9];
  const float* b3 = (const float*)d_in[10];
  const float* w4 = (const float*)d_in[11];
  const float* b4 = (const float*)d_in[12];
  float* out = (float*)d_out;

  unsigned* pk = (unsigned*)d_ws;  // 165888 dwords

  ns_poly_k<<<320, 512, 0, stream>>>(w1, w2, w3, w4, w_in, w_out, pk);
  fused_k<4><<<1024, 256, 0, stream>>>(x, pk, b_in, b1, b2, b3, b4, b_out, out);
}